// Round 7
// baseline (2783.315 us; speedup 1.0000x reference)
//
#include <hip/hip_runtime.h>
#include <math.h>

#define NCR 256      // B*NC crane nodes
#define NPI 16384    // B*NP pile nodes

typedef __attribute__((ext_vector_type(8))) short bf16x8;
typedef __attribute__((ext_vector_type(4))) float f32x4;

__device__ __forceinline__ float eluf(float x){ return x > 0.f ? x : expm1f(x); }
__device__ __forceinline__ float geluf(float x){
  float t = tanhf(0.7978845608028654f * (x + 0.044715f * x * x * x));
  return 0.5f * x * (1.f + t);
}
__device__ __forceinline__ unsigned short f2bf(float x){
  unsigned int u = __float_as_uint(x);
  unsigned int r = u + 0x7fffu + ((u >> 16) & 1u);
  return (unsigned short)(r >> 16);
}
__device__ __forceinline__ unsigned int pack2(float lo, float hi){
  return (unsigned int)f2bf(lo) | ((unsigned int)f2bf(hi) << 16);
}
// monotonic float->uint key (order-preserving), for LDS atomicMax on floats
__device__ __forceinline__ unsigned int fkey(float x){
  unsigned int u = __float_as_uint(x);
  return (u & 0x80000000u) ? ~u : (u | 0x80000000u);
}
__device__ __forceinline__ float funkey(unsigned int k){
  return __uint_as_float((k & 0x80000000u) ? (k ^ 0x80000000u) : ~k);
}

__global__ void fill_kernel(float* __restrict__ p, float v, int n){
  int i = blockIdx.x * 256 + threadIdx.x;
  if (i < n) p[i] = v;
}

__global__ void gelu_kernel(float* __restrict__ a, int n){
  int i = blockIdx.x * 256 + threadIdx.x;
  if (i < n) a[i] = geluf(a[i]);
}

__global__ void skip_elu_kernel(const float* __restrict__ o, const float* __restrict__ xold,
                                const float* __restrict__ skipv, int use_skip,
                                float* __restrict__ xnew, int n){
  int i = blockIdx.x * 256 + threadIdx.x;
  if (i >= n) return;
  float v = o[i];
  if (use_skip){
    float g = 1.f / (1.f + expf(-skipv[0]));
    v = g * v + (1.f - g) * xold[i];
  }
  xnew[i] = eluf(v);
}

// ---------------- generic f32 GEMM: C = act(A@W + bias) -------------------
template<int ACT>
__global__ __launch_bounds__(256) void gemm128(
    const float* __restrict__ Am, int lda,
    const float* __restrict__ W, int ldw,
    const float* __restrict__ bias,
    float* __restrict__ C, int ldc,
    int M, int N, int K)
{
  __shared__ float As[16][132];
  __shared__ float Bs[16][132];
  const int tid = threadIdx.x;
  const int m0 = blockIdx.y * 128, n0 = blockIdx.x * 128;
  const int tx = tid & 15, ty = tid >> 4;
  float acc[8][8];
#pragma unroll
  for (int i = 0; i < 8; ++i)
#pragma unroll
    for (int j = 0; j < 8; ++j) acc[i][j] = 0.f;

  const int ra = tid >> 2, ca = (tid & 3) << 2;
  const int rb = tid >> 5, cbn = (tid & 31) << 2;

  for (int k0 = 0; k0 < K; k0 += 16){
#pragma unroll
    for (int half = 0; half < 2; ++half){
      int r = ra + half * 64;
      int m = m0 + r;
      float4 v = make_float4(0.f, 0.f, 0.f, 0.f);
      if (m < M) v = *(const float4*)(Am + (size_t)m * lda + k0 + ca);
      As[ca + 0][r] = v.x; As[ca + 1][r] = v.y;
      As[ca + 2][r] = v.z; As[ca + 3][r] = v.w;
    }
#pragma unroll
    for (int half = 0; half < 2; ++half){
      int k = k0 + rb + half * 8;
      *(float4*)&Bs[rb + half * 8][cbn] = *(const float4*)(W + (size_t)k * ldw + n0 + cbn);
    }
    __syncthreads();
#pragma unroll
    for (int k = 0; k < 16; ++k){
      float a[8], b[8];
      *(float4*)&a[0] = *(const float4*)&As[k][ty * 8];
      *(float4*)&a[4] = *(const float4*)&As[k][ty * 8 + 4];
      *(float4*)&b[0] = *(const float4*)&Bs[k][tx * 8];
      *(float4*)&b[4] = *(const float4*)&Bs[k][tx * 8 + 4];
#pragma unroll
      for (int i = 0; i < 8; ++i)
#pragma unroll
        for (int j = 0; j < 8; ++j) acc[i][j] = fmaf(a[i], b[j], acc[i][j]);
    }
    __syncthreads();
  }
#pragma unroll
  for (int i = 0; i < 8; ++i){
    int m = m0 + ty * 8 + i;
    if (m >= M) continue;
#pragma unroll
    for (int j = 0; j < 8; ++j){
      int n = n0 + tx * 8 + j;
      float v = acc[i][j] + (bias ? bias[n] : 0.f);
      if (ACT == 1) v = eluf(v);
      C[(size_t)m * ldc + n] = v;
    }
  }
}

// ------ P0cp[b*4+c][n] = P0c[b*4+c][n] + ab0[n] + sum_k hpool[b][k]*aw0[512+k][n]
__global__ void p0cp_kernel(const float* __restrict__ hpool, const float* __restrict__ aw0,
                            const float* __restrict__ ab0, const float* __restrict__ P0c,
                            float* __restrict__ P0cp){
  int idx = blockIdx.x * 256 + threadIdx.x;   // 64*1024
  int b = idx >> 10, n = idx & 1023;
  const float* hb = hpool + b * 512;
  float s = ab0[n];
  for (int k = 0; k < 512; ++k) s = fmaf(hb[k], aw0[(size_t)(512 + k) * 1024 + n], s);
#pragma unroll
  for (int c = 0; c < 4; ++c)
    P0cp[(size_t)(b * 4 + c) * 1024 + n] = s + P0c[(size_t)(b * 4 + c) * 1024 + n];
}

// ------ aw1T[n][k] = bf16(aw1[k][n]) ------
__global__ void aw1t_kernel(const float* __restrict__ aw1, unsigned short* __restrict__ aw1T){
  __shared__ float t[32][33];
  int k0 = blockIdx.x * 32, n0 = blockIdx.y * 32;
  int tid = threadIdx.x;
  int r = tid >> 3, c4 = (tid & 7) * 4;
  float4 v = *(const float4*)(aw1 + (size_t)(k0 + r) * 1024 + n0 + c4);
  t[r][c4] = v.x; t[r][c4+1] = v.y; t[r][c4+2] = v.z; t[r][c4+3] = v.w;
  __syncthreads();
  ushort4 o;
  o.x = f2bf(t[c4+0][r]); o.y = f2bf(t[c4+1][r]);
  o.z = f2bf(t[c4+2][r]); o.w = f2bf(t[c4+3][r]);
  *(ushort4*)&aw1T[(size_t)(n0 + r) * 1024 + k0 + c4] = o;
}

// ------ h0c[pi][n] = bf16(elu(P0p[pi][n] + P0cp[(pi>>8)*4 + c][n])) ------
__global__ void h0_build(const float* __restrict__ P0p, const float* __restrict__ P0cp,
                         int c, unsigned short* __restrict__ h0c){
  int t = blockIdx.x * 256 + threadIdx.x;      // [0, 2,097,152)
  int pi = t >> 7, n8 = (t & 127) << 3;
  int b = pi >> 8;
  const float* pp = P0p + (size_t)pi * 1024 + n8;
  const float* pc = P0cp + (size_t)(b * 4 + c) * 1024 + n8;
  float v[8], u[8];
  *(float4*)&v[0] = *(const float4*)pp;
  *(float4*)&v[4] = *(const float4*)(pp + 4);
  *(float4*)&u[0] = *(const float4*)pc;
  *(float4*)&u[4] = *(const float4*)(pc + 4);
  float r[8];
#pragma unroll
  for (int i = 0; i < 8; ++i) r[i] = eluf(v[i] + u[i]);
  uint4 o;
  o.x = pack2(r[0], r[1]); o.y = pack2(r[2], r[3]);
  o.z = pack2(r[4], r[5]); o.w = pack2(r[6], r[7]);
  *(uint4*)&h0c[(size_t)pi * 1024 + n8] = o;
}

// ---- fused actor MFMA (per crane c): h1=elu(h0c@aw1+ab1); logits[pi*4+c] += h1@aw2
__global__ __launch_bounds__(256) void actor_mfma(
    const unsigned short* __restrict__ h0c, const unsigned short* __restrict__ aw1T,
    const float* __restrict__ ab1, const float* __restrict__ aw2,
    int c, float* __restrict__ logits)
{
  __shared__ unsigned short As[128][72];
  __shared__ unsigned short Bs[128][72];
  const int tid = threadIdx.x;
  const int m0 = blockIdx.y * 128, n0 = blockIdx.x * 128;
  const int w = tid >> 6, lane = tid & 63;
  const int wm = w >> 1, wn = w & 1;
  const int col = lane & 15, quad = lane >> 4;

  f32x4 zero = {0.f, 0.f, 0.f, 0.f};
  f32x4 acc[4][4];
#pragma unroll
  for (int mi = 0; mi < 4; ++mi)
#pragma unroll
    for (int ni = 0; ni < 4; ++ni) acc[mi][ni] = zero;

  const int srow = tid >> 1, skb = (tid & 1) * 32;

  for (int k0 = 0; k0 < 1024; k0 += 64){
    const uint4* ga = (const uint4*)(h0c  + (size_t)(m0 + srow) * 1024 + k0 + skb);
    const uint4* gb = (const uint4*)(aw1T + (size_t)(n0 + srow) * 1024 + k0 + skb);
    uint4 a0 = ga[0], a1 = ga[1], a2 = ga[2], a3 = ga[3];
    uint4 b0 = gb[0], b1 = gb[1], b2 = gb[2], b3 = gb[3];
    __syncthreads();
    *(uint4*)&As[srow][skb +  0] = a0; *(uint4*)&As[srow][skb +  8] = a1;
    *(uint4*)&As[srow][skb + 16] = a2; *(uint4*)&As[srow][skb + 24] = a3;
    *(uint4*)&Bs[srow][skb +  0] = b0; *(uint4*)&Bs[srow][skb +  8] = b1;
    *(uint4*)&Bs[srow][skb + 16] = b2; *(uint4*)&Bs[srow][skb + 24] = b3;
    __syncthreads();
#pragma unroll
    for (int kk = 0; kk < 2; ++kk){
      const int kidx = kk * 32 + quad * 8;
      bf16x8 af[4], bfr[4];
      const int rA = wm * 64 + col, rB = wn * 64 + col;
#pragma unroll
      for (int mi = 0; mi < 4; ++mi) af[mi] = *(const bf16x8*)&As[rA + mi * 16][kidx];
#pragma unroll
      for (int ni = 0; ni < 4; ++ni) bfr[ni] = *(const bf16x8*)&Bs[rB + ni * 16][kidx];
#pragma unroll
      for (int mi = 0; mi < 4; ++mi)
#pragma unroll
        for (int ni = 0; ni < 4; ++ni)
          acc[mi][ni] = __builtin_amdgcn_mfma_f32_16x16x32_bf16(af[mi], bfr[ni], acc[mi][ni], 0, 0, 0);
    }
  }

  float part[4][4];
#pragma unroll
  for (int mi = 0; mi < 4; ++mi)
#pragma unroll
    for (int r = 0; r < 4; ++r) part[mi][r] = 0.f;
#pragma unroll
  for (int ni = 0; ni < 4; ++ni){
    int n = n0 + wn * 64 + ni * 16 + col;
    float b1v = ab1[n], w2v = aw2[n];
#pragma unroll
    for (int mi = 0; mi < 4; ++mi)
#pragma unroll
      for (int r = 0; r < 4; ++r)
        part[mi][r] += eluf(acc[mi][ni][r] + b1v) * w2v;
  }
#pragma unroll
  for (int msk = 1; msk <= 8; msk <<= 1)
#pragma unroll
    for (int mi = 0; mi < 4; ++mi)
#pragma unroll
      for (int r = 0; r < 4; ++r)
        part[mi][r] += __shfl_xor(part[mi][r], msk);
  if (col == 0){
#pragma unroll
    for (int mi = 0; mi < 4; ++mi)
#pragma unroll
      for (int r = 0; r < 4; ++r){
        int pi = m0 + wm * 64 + mi * 16 + quad * 4 + r;
        atomicAdd(&logits[pi * 4 + c], part[mi][r]);
      }
  }
}

// ------------- per-head D×D relation transforms: krel/vrel ----------------
__global__ __launch_bounds__(256) void rel_kernel(
    const float* __restrict__ Kt, const float* __restrict__ Vt,
    const float* __restrict__ arel, const float* __restrict__ mrel,
    float* __restrict__ krel, float* __restrict__ vrel)
{
  const int h = blockIdx.y, n0 = blockIdx.x * 32;
  __shared__ float Ams[32][33], Mms[32][33], Kr[32][33], Vr[32][33];
  const int tid = threadIdx.x;
  {
    int idx = tid * 4; int d = idx >> 5, e = idx & 31;
    float4 va = *(const float4*)(arel + h * 1024 + idx);
    float4 vm = *(const float4*)(mrel + h * 1024 + idx);
    Ams[d][e] = va.x; Ams[d][e+1] = va.y; Ams[d][e+2] = va.z; Ams[d][e+3] = va.w;
    Mms[d][e] = vm.x; Mms[d][e+1] = vm.y; Mms[d][e+2] = vm.z; Mms[d][e+3] = vm.w;
  }
  {
    int i = tid >> 3, d4 = (tid & 7) << 2;
    float4 vk = *(const float4*)(Kt + (size_t)(n0 + i) * 256 + h * 32 + d4);
    float4 vv = *(const float4*)(Vt + (size_t)(n0 + i) * 256 + h * 32 + d4);
    Kr[i][d4] = vk.x; Kr[i][d4+1] = vk.y; Kr[i][d4+2] = vk.z; Kr[i][d4+3] = vk.w;
    Vr[i][d4] = vv.x; Vr[i][d4+1] = vv.y; Vr[i][d4+2] = vv.z; Vr[i][d4+3] = vv.w;
  }
  __syncthreads();
  const int i = tid >> 3, e0 = (tid & 7) << 2;
  float aK[4] = {0,0,0,0}, aV[4] = {0,0,0,0};
#pragma unroll 8
  for (int d = 0; d < 32; ++d){
    float kv = Kr[i][d], vv = Vr[i][d];
#pragma unroll
    for (int e = 0; e < 4; ++e){
      aK[e] = fmaf(kv, Ams[d][e0 + e], aK[e]);
      aV[e] = fmaf(vv, Mms[d][e0 + e], aV[e]);
    }
  }
#pragma unroll
  for (int e = 0; e < 4; ++e){
    krel[(size_t)(n0 + i) * 256 + h * 32 + e0 + e] = aK[e];
    vrel[(size_t)(n0 + i) * 256 + h * 32 + e0 + e] = aV[e];
  }
}

// -------- per-(graph,head) fully-LDS edge attention + aggregation ---------
// grid (B, 8), 256 threads. Stages Q/K/V head-slices node-major [N][33]
// (bank = (node+f)&31, conflict-free), runs 3-pass softmax over edges and
// the weighted scatter entirely in LDS, writes agg once.
template<int NSRC, int NDST, int EPG, int ACCUM>
__global__ __launch_bounds__(256) void edge_dense(
    const int* __restrict__ ei, int Er,
    const float* __restrict__ Q, const float* __restrict__ krel,
    const float* __restrict__ vrel, const float* __restrict__ prel,
    float* __restrict__ aggOut)
{
  const int b = blockIdx.x, h = blockIdx.y;
  __shared__ float Ks[NSRC][33];
  __shared__ float Vs[NSRC][33];
  __shared__ float Qs[NDST][33];
  __shared__ float aex[EPG];
  __shared__ unsigned int smax[NDST];
  __shared__ float ssum[NDST];
  __shared__ float agg[NDST][33];
  const int tid = threadIdx.x;
  const unsigned int NEGINF_KEY = 0x007FFFFFu;  // fkey(-inf)

  for (int i = tid; i < NSRC * 32; i += 256){
    int s = i >> 5, f = i & 31;
    Ks[s][f] = krel[(size_t)(b * NSRC + s) * 256 + h * 32 + f];
    Vs[s][f] = vrel[(size_t)(b * NSRC + s) * 256 + h * 32 + f];
  }
  for (int i = tid; i < NDST * 32; i += 256){
    int d = i >> 5, f = i & 31;
    Qs[d][f] = Q[(size_t)(b * NDST + d) * 256 + h * 32 + f];
  }
  for (int i = tid; i < NDST; i += 256){ smax[i] = NEGINF_KEY; ssum[i] = 0.f; }
  for (int i = tid; i < NDST * 33; i += 256) ((float*)agg)[i] = 0.f;
  __syncthreads();

  const int ebase = b * EPG;
  const float sc = prel[h] * 0.17677669529663687f;   // 1/sqrt(32)
  // A1: logits + per-dst max
  for (int idx = tid; idx < EPG; idx += 256){
    int sl = ei[ebase + idx] - b * NSRC;
    int dl = ei[Er + ebase + idx] - b * NDST;
    float s = 0.f;
#pragma unroll
    for (int f = 0; f < 32; ++f) s = fmaf(Qs[dl][f], Ks[sl][f], s);
    s *= sc;
    aex[idx] = s;
    atomicMax(&smax[dl], fkey(s));
  }
  __syncthreads();
  // A2: exp + per-dst sum
  for (int idx = tid; idx < EPG; idx += 256){
    int dl = ei[Er + ebase + idx] - b * NDST;
    float ex = expf(aex[idx] - funkey(smax[dl]));
    aex[idx] = ex;
    atomicAdd(&ssum[dl], ex);
  }
  __syncthreads();
  // A3: normalize
  for (int idx = tid; idx < EPG; idx += 256){
    int dl = ei[Er + ebase + idx] - b * NDST;
    aex[idx] = aex[idx] / ssum[dl];
  }
  __syncthreads();
  // B: weighted scatter, all LDS
  const int f = tid & 31, eo = tid >> 5;
  for (int it = eo; it < EPG; it += 8){
    int e = ebase + it;
    int sl = ei[e] - b * NSRC;
    int dl = ei[Er + e] - b * NDST;
    atomicAdd(&agg[dl][f], aex[it] * Vs[sl][f]);
  }
  __syncthreads();
  for (int i = tid; i < NDST * 32; i += 256){
    int dl = i >> 5, ff = i & 31;
    float val = agg[dl][ff];
    float* op = &aggOut[(size_t)(b * NDST + dl) * 256 + h * 32 + ff];
    if (ACCUM) *op += val; else *op = val;
  }
}

// ------------------------------ pooling -----------------------------------
__global__ void pool_kernel(const float* __restrict__ xc, const float* __restrict__ xp,
                            float* __restrict__ hpool){
  int b = blockIdx.x, e = threadIdx.x;   // 256 threads
  float s = 0.f;
#pragma unroll
  for (int c = 0; c < 4; ++c) s += xc[(size_t)(b * 4 + c) * 256 + e];
  hpool[b * 512 + e] = s * 0.25f;
  float s2 = 0.f;
  for (int p = 0; p < 256; ++p) s2 += xp[(size_t)(b * 256 + p) * 256 + e];
  hpool[b * 512 + 256 + e] = s2 * (1.f / 256.f);
}

// ------------------------- outputs ---------------------------------------
__global__ void logsoftmax_out(const float* __restrict__ logits,
                               const int* __restrict__ action, float* __restrict__ out){
  int b = blockIdx.x, tid = threadIdx.x;
  const float* row = logits + b * 1024;
  __shared__ float red[256];
  float m = -INFINITY;
  for (int i = tid; i < 1024; i += 256) m = fmaxf(m, row[i]);
  red[tid] = m; __syncthreads();
  for (int s = 128; s > 0; s >>= 1){ if (tid < s) red[tid] = fmaxf(red[tid], red[tid + s]); __syncthreads(); }
  m = red[0]; __syncthreads();
  float s = 0.f;
  for (int i = tid; i < 1024; i += 256) s += expf(row[i] - m);
  red[tid] = s; __syncthreads();
  for (int st = 128; st > 0; st >>= 1){ if (tid < st) red[tid] += red[tid + st]; __syncthreads(); }
  if (tid == 0) out[b] = row[action[b]] - m - logf(red[0]);
}

__global__ void critic_out(const float* __restrict__ h2, const float* __restrict__ cw2,
                           const float* __restrict__ cb2, float* __restrict__ out){
  int b = blockIdx.x, tid = threadIdx.x;
  __shared__ float red[256];
  float s = 0.f;
  for (int i = tid; i < 512; i += 256) s += h2[b * 512 + i] * cw2[i];
  red[tid] = s; __syncthreads();
  for (int st = 128; st > 0; st >>= 1){ if (tid < st) red[tid] += red[tid + st]; __syncthreads(); }
  if (tid == 0) out[64 + b] = red[0] + cb2[0];
}

extern "C" void kernel_launch(void* const* d_in, const int* in_sizes, int n_in,
                              void* d_out, int out_size, void* d_ws, size_t ws_size,
                              hipStream_t stream)
{
  const float* x_crane = (const float*)d_in[0];
  const float* x_pile  = (const float*)d_in[1];
  const int* e_list[4] = {(const int*)d_in[2], (const int*)d_in[3],
                          (const int*)d_in[4], (const int*)d_in[5]};
  int E_cnt[4]; for (int r = 0; r < 4; ++r) E_cnt[r] = in_sizes[2 + r] / 2;
  const int*   batch_action = (const int*)d_in[6];
  const float* kqv_w[2] = {(const float*)d_in[8],  (const float*)d_in[10]};
  const float* kqv_b[2] = {(const float*)d_in[9],  (const float*)d_in[11]};
  const float* a_rel = (const float*)d_in[12];
  const float* m_rel = (const float*)d_in[13];
  const float* p_rel = (const float*)d_in[14];
  const float* out_w = (const float*)d_in[15];
  const float* out_b = (const float*)d_in[16];
  const float* skip  = (const float*)d_in[17];
  const float* aw0 = (const float*)d_in[18]; const float* ab0 = (const float*)d_in[19];
  const float* aw1 = (const float*)d_in[20]; const float* ab1 = (const float*)d_in[21];
  const float* aw2 = (const float*)d_in[22];
  const float* cw0 = (const float*)d_in[24]; const float* cb0 = (const float*)d_in[25];
  const float* cw1 = (const float*)d_in[26]; const float* cb1 = (const float*)d_in[27];
  const float* cw2 = (const float*)d_in[28]; const float* cb2 = (const float*)d_in[29];
  float* out = (float*)d_out;

  float* w = (float*)d_ws;
  size_t o = 0;
  auto A = [&](size_t n){ float* p = w + o; o += n; return p; };
  float* Kc = A(65536);     float* Qc = A(65536);     float* Vc = A(65536);
  float* Kp = A(4194304);   float* Qp = A(4194304);   float* Vp = A(4194304);
  float* krc = A(65536);    float* vrc = A(65536);
  float* krp = A(4194304);  float* vrp = A(4194304);
  float* aggc = A(65536);   float* aggp = A(4194304);
  float* xc0 = A(65536);    float* xc1 = A(65536);
  float* xp0 = A(4194304);  float* xp1 = A(4194304);
  float* alpha = A(2097152);
  float* segmax = A(131072); float* segsum = A(131072);
  float* hpool = A(32768);
  // ---- post-HGT overlays (all verified disjoint from live xc1/xp1/hpool) ----
  float*          P0p  = w;                        // [0, 16,777,216) f32 — dead
  unsigned short* h0c  = (unsigned short*)(w + 16777216); // [16.77M, 25.17M) f32-equiv
  unsigned short* aw1T = (unsigned short*)xp0;     // in dead xp0
  float*          P0cp = alpha;                    // 262,144
  float*          P0c  = alpha + 262144;           // 262,144
  float*          logits = segmax;                 // 65,536
  float*          ch1 = segsum;                    // 32,768
  float*          ch2 = segsum + 65536;            // 32,768

  for (int l = 0; l < 2; ++l){
    const float* xc_in = l ? xc0 : x_crane;
    const float* xp_in = l ? xp0 : x_pile;
    const int Kd = l ? 256 : 64;
    for (int j = 0; j < 3; ++j){
      float* Cc = (j == 0) ? Kc : (j == 1) ? Qc : Vc;
      float* Cp = (j == 0) ? Kp : (j == 1) ? Qp : Vp;
      gemm128<0><<<dim3(2, 2),   256, 0, stream>>>(xc_in, Kd, kqv_w[l] + (size_t)j * Kd * 256,       256, kqv_b[l] + j * 256,       Cc, 256, NCR, 256, Kd);
      gemm128<0><<<dim3(2, 128), 256, 0, stream>>>(xp_in, Kd, kqv_w[l] + (size_t)(3 + j) * Kd * 256, 256, kqv_b[l] + (3 + j) * 256, Cp, 256, NPI, 256, Kd);
    }
    // r0: cc (src crane, dst crane)
    rel_kernel<<<dim3(NCR / 32, 8), 256, 0, stream>>>(Kc, Vc,
        a_rel + (size_t)(l * 4 + 0) * 8192, m_rel + (size_t)(l * 4 + 0) * 8192, krc, vrc);
    edge_dense<4, 4, 16, 0><<<dim3(64, 8), 256, 0, stream>>>(
        e_list[0], E_cnt[0], Qc, krc, vrc, p_rel + (l * 4 + 0) * 8, aggc);
    // r1: pc (src pile, dst crane)
    rel_kernel<<<dim3(NPI / 32, 8), 256, 0, stream>>>(Kp, Vp,
        a_rel + (size_t)(l * 4 + 1) * 8192, m_rel + (size_t)(l * 4 + 1) * 8192, krp, vrp);
    edge_dense<256, 4, 1024, 1><<<dim3(64, 8), 256, 0, stream>>>(
        e_list[1], E_cnt[1], Qc, krp, vrp, p_rel + (l * 4 + 1) * 8, aggc);
    // r2: cp (src crane, dst pile)
    rel_kernel<<<dim3(NCR / 32, 8), 256, 0, stream>>>(Kc, Vc,
        a_rel + (size_t)(l * 4 + 2) * 8192, m_rel + (size_t)(l * 4 + 2) * 8192, krc, vrc);
    edge_dense<4, 256, 1024, 0><<<dim3(64, 8), 256, 0, stream>>>(
        e_list[2], E_cnt[2], Qp, krc, vrc, p_rel + (l * 4 + 2) * 8, aggp);
    // r3: pp (src pile, dst pile)
    rel_kernel<<<dim3(NPI / 32, 8), 256, 0, stream>>>(Kp, Vp,
        a_rel + (size_t)(l * 4 + 3) * 8192, m_rel + (size_t)(l * 4 + 3) * 8192, krp, vrp);
    edge_dense<256, 256, 4096, 1><<<dim3(64, 8), 256, 0, stream>>>(
        e_list[3], E_cnt[3], Qp, krp, vrp, p_rel + (l * 4 + 3) * 8, aggp);

    gelu_kernel<<<256,   256, 0, stream>>>(aggc, 65536);
    gelu_kernel<<<16384, 256, 0, stream>>>(aggp, 4194304);
    gemm128<0><<<dim3(2, 2),   256, 0, stream>>>(aggc, 256, out_w + (size_t)(l * 2 + 0) * 65536, 256, out_b + (l * 2 + 0) * 256, Kc, 256, NCR, 256, 256);
    gemm128<0><<<dim3(2, 128), 256, 0, stream>>>(aggp, 256, out_w + (size_t)(l * 2 + 1) * 65536, 256, out_b + (l * 2 + 1) * 256, Kp, 256, NPI, 256, 256);
    skip_elu_kernel<<<256,   256, 0, stream>>>(Kc, xc_in, skip + l * 2 + 0, l, l ? xc1 : xc0, 65536);
    skip_elu_kernel<<<16384, 256, 0, stream>>>(Kp, xp_in, skip + l * 2 + 1, l, l ? xp1 : xp0, 4194304);
  }

  // ---- pooling + actor layer0 decomposition ----
  pool_kernel<<<64, 256, 0, stream>>>(xc1, xp1, hpool);
  gemm128<0><<<dim3(8, 2), 256, 0, stream>>>(xc1, 256, aw0, 1024, nullptr, P0c, 1024, NCR, 1024, 256);
  p0cp_kernel<<<256, 256, 0, stream>>>(hpool, aw0, ab0, P0c, P0cp);
  aw1t_kernel<<<dim3(32, 32), 256, 0, stream>>>(aw1, aw1T);
  gemm128<0><<<dim3(8, 128), 256, 0, stream>>>(xp1, 256, aw0 + (size_t)256 * 1024, 1024, nullptr, P0p, 1024, NPI, 1024, 256);
  fill_kernel<<<256, 256, 0, stream>>>(logits, 0.f, 65536);
  for (int c = 0; c < 4; ++c){
    h0_build<<<8192, 256, 0, stream>>>(P0p, P0cp, c, h0c);
    actor_mfma<<<dim3(8, 128), 256, 0, stream>>>(h0c, aw1T, ab1, aw2, c, logits);
  }
  logsoftmax_out<<<64, 256, 0, stream>>>(logits, batch_action, out);

  // critic
  gemm128<1><<<dim3(4, 1), 256, 0, stream>>>(hpool, 512, cw0, 512, cb0, ch1, 512, 64, 512, 512);
  gemm128<1><<<dim3(4, 1), 256, 0, stream>>>(ch1,   512, cw1, 512, cb1, ch2, 512, 64, 512, 512);
  critic_out<<<64, 256, 0, stream>>>(ch2, cw2, cb2, out);
}

// Round 8
// 2320.252 us; speedup vs baseline: 1.1996x; 1.1996x over previous
//
#include <hip/hip_runtime.h>
#include <math.h>

#define NCR 256      // B*NC crane nodes
#define NPI 16384    // B*NP pile nodes

typedef __attribute__((ext_vector_type(8))) short bf16x8;
typedef __attribute__((ext_vector_type(4))) float f32x4;

__device__ __forceinline__ float eluf(float x){ return x > 0.f ? x : expm1f(x); }
__device__ __forceinline__ float geluf(float x){
  float t = tanhf(0.7978845608028654f * (x + 0.044715f * x * x * x));
  return 0.5f * x * (1.f + t);
}
__device__ __forceinline__ unsigned short f2bf(float x){
  unsigned int u = __float_as_uint(x);
  unsigned int r = u + 0x7fffu + ((u >> 16) & 1u);
  return (unsigned short)(r >> 16);
}
__device__ __forceinline__ unsigned int pack2(float lo, float hi){
  return (unsigned int)f2bf(lo) | ((unsigned int)f2bf(hi) << 16);
}

__global__ void fill_kernel(float* __restrict__ p, float v, int n){
  int i = blockIdx.x * 256 + threadIdx.x;
  if (i < n) p[i] = v;
}

__global__ void gelu_kernel(float* __restrict__ a, int n){
  int i = blockIdx.x * 256 + threadIdx.x;
  if (i < n) a[i] = geluf(a[i]);
}

__global__ void skip_elu_kernel(const float* __restrict__ o, const float* __restrict__ xold,
                                const float* __restrict__ skipv, int use_skip,
                                float* __restrict__ xnew, int n){
  int i = blockIdx.x * 256 + threadIdx.x;
  if (i >= n) return;
  float v = o[i];
  if (use_skip){
    float g = 1.f / (1.f + expf(-skipv[0]));
    v = g * v + (1.f - g) * xold[i];
  }
  xnew[i] = eluf(v);
}

// ---------------- generic f32 GEMM: C = act(A@W + bias) -------------------
template<int ACT>
__global__ __launch_bounds__(256) void gemm128(
    const float* __restrict__ Am, int lda,
    const float* __restrict__ W, int ldw,
    const float* __restrict__ bias,
    float* __restrict__ C, int ldc,
    int M, int N, int K)
{
  __shared__ float As[16][132];
  __shared__ float Bs[16][132];
  const int tid = threadIdx.x;
  const int m0 = blockIdx.y * 128, n0 = blockIdx.x * 128;
  const int tx = tid & 15, ty = tid >> 4;
  float acc[8][8];
#pragma unroll
  for (int i = 0; i < 8; ++i)
#pragma unroll
    for (int j = 0; j < 8; ++j) acc[i][j] = 0.f;

  const int ra = tid >> 2, ca = (tid & 3) << 2;
  const int rb = tid >> 5, cbn = (tid & 31) << 2;

  for (int k0 = 0; k0 < K; k0 += 16){
#pragma unroll
    for (int half = 0; half < 2; ++half){
      int r = ra + half * 64;
      int m = m0 + r;
      float4 v = make_float4(0.f, 0.f, 0.f, 0.f);
      if (m < M) v = *(const float4*)(Am + (size_t)m * lda + k0 + ca);
      As[ca + 0][r] = v.x; As[ca + 1][r] = v.y;
      As[ca + 2][r] = v.z; As[ca + 3][r] = v.w;
    }
#pragma unroll
    for (int half = 0; half < 2; ++half){
      int k = k0 + rb + half * 8;
      *(float4*)&Bs[rb + half * 8][cbn] = *(const float4*)(W + (size_t)k * ldw + n0 + cbn);
    }
    __syncthreads();
#pragma unroll
    for (int k = 0; k < 16; ++k){
      float a[8], b[8];
      *(float4*)&a[0] = *(const float4*)&As[k][ty * 8];
      *(float4*)&a[4] = *(const float4*)&As[k][ty * 8 + 4];
      *(float4*)&b[0] = *(const float4*)&Bs[k][tx * 8];
      *(float4*)&b[4] = *(const float4*)&Bs[k][tx * 8 + 4];
#pragma unroll
      for (int i = 0; i < 8; ++i)
#pragma unroll
        for (int j = 0; j < 8; ++j) acc[i][j] = fmaf(a[i], b[j], acc[i][j]);
    }
    __syncthreads();
  }
#pragma unroll
  for (int i = 0; i < 8; ++i){
    int m = m0 + ty * 8 + i;
    if (m >= M) continue;
#pragma unroll
    for (int j = 0; j < 8; ++j){
      int n = n0 + tx * 8 + j;
      float v = acc[i][j] + (bias ? bias[n] : 0.f);
      if (ACT == 1) v = eluf(v);
      C[(size_t)m * ldc + n] = v;
    }
  }
}

// ------ P0cp[b*4+c][n] = P0c[b*4+c][n] + ab0[n] + sum_k hpool[b][k]*aw0[512+k][n]
__global__ void p0cp_kernel(const float* __restrict__ hpool, const float* __restrict__ aw0,
                            const float* __restrict__ ab0, const float* __restrict__ P0c,
                            float* __restrict__ P0cp){
  int idx = blockIdx.x * 256 + threadIdx.x;   // 64*1024
  int b = idx >> 10, n = idx & 1023;
  const float* hb = hpool + b * 512;
  float s = ab0[n];
  for (int k = 0; k < 512; ++k) s = fmaf(hb[k], aw0[(size_t)(512 + k) * 1024 + n], s);
#pragma unroll
  for (int c = 0; c < 4; ++c)
    P0cp[(size_t)(b * 4 + c) * 1024 + n] = s + P0c[(size_t)(b * 4 + c) * 1024 + n];
}

// ------ aw1T[n][k] = bf16(aw1[k][n]) ------
__global__ void aw1t_kernel(const float* __restrict__ aw1, unsigned short* __restrict__ aw1T){
  __shared__ float t[32][33];
  int k0 = blockIdx.x * 32, n0 = blockIdx.y * 32;
  int tid = threadIdx.x;
  int r = tid >> 3, c4 = (tid & 7) * 4;
  float4 v = *(const float4*)(aw1 + (size_t)(k0 + r) * 1024 + n0 + c4);
  t[r][c4] = v.x; t[r][c4+1] = v.y; t[r][c4+2] = v.z; t[r][c4+3] = v.w;
  __syncthreads();
  ushort4 o;
  o.x = f2bf(t[c4+0][r]); o.y = f2bf(t[c4+1][r]);
  o.z = f2bf(t[c4+2][r]); o.w = f2bf(t[c4+3][r]);
  *(ushort4*)&aw1T[(size_t)(n0 + r) * 1024 + k0 + c4] = o;
}

// ------ h0c[pi][n] = bf16(elu(P0p[pi][n] + P0cp[(pi>>8)*4 + c][n])) ------
__global__ void h0_build(const float* __restrict__ P0p, const float* __restrict__ P0cp,
                         int c, unsigned short* __restrict__ h0c){
  int t = blockIdx.x * 256 + threadIdx.x;      // [0, 2,097,152)
  int pi = t >> 7, n8 = (t & 127) << 3;
  int b = pi >> 8;
  const float* pp = P0p + (size_t)pi * 1024 + n8;
  const float* pc = P0cp + (size_t)(b * 4 + c) * 1024 + n8;
  float v[8], u[8];
  *(float4*)&v[0] = *(const float4*)pp;
  *(float4*)&v[4] = *(const float4*)(pp + 4);
  *(float4*)&u[0] = *(const float4*)pc;
  *(float4*)&u[4] = *(const float4*)(pc + 4);
  float r[8];
#pragma unroll
  for (int i = 0; i < 8; ++i) r[i] = eluf(v[i] + u[i]);
  uint4 o;
  o.x = pack2(r[0], r[1]); o.y = pack2(r[2], r[3]);
  o.z = pack2(r[4], r[5]); o.w = pack2(r[6], r[7]);
  *(uint4*)&h0c[(size_t)pi * 1024 + n8] = o;
}

// ---- fused actor MFMA (per crane c): h1=elu(h0c@aw1+ab1); logits[pi*4+c] += h1@aw2
__global__ __launch_bounds__(256) void actor_mfma(
    const unsigned short* __restrict__ h0c, const unsigned short* __restrict__ aw1T,
    const float* __restrict__ ab1, const float* __restrict__ aw2,
    int c, float* __restrict__ logits)
{
  __shared__ unsigned short As[128][72];
  __shared__ unsigned short Bs[128][72];
  const int tid = threadIdx.x;
  const int m0 = blockIdx.y * 128, n0 = blockIdx.x * 128;
  const int w = tid >> 6, lane = tid & 63;
  const int wm = w >> 1, wn = w & 1;
  const int col = lane & 15, quad = lane >> 4;

  f32x4 zero = {0.f, 0.f, 0.f, 0.f};
  f32x4 acc[4][4];
#pragma unroll
  for (int mi = 0; mi < 4; ++mi)
#pragma unroll
    for (int ni = 0; ni < 4; ++ni) acc[mi][ni] = zero;

  const int srow = tid >> 1, skb = (tid & 1) * 32;

  for (int k0 = 0; k0 < 1024; k0 += 64){
    const uint4* ga = (const uint4*)(h0c  + (size_t)(m0 + srow) * 1024 + k0 + skb);
    const uint4* gb = (const uint4*)(aw1T + (size_t)(n0 + srow) * 1024 + k0 + skb);
    uint4 a0 = ga[0], a1 = ga[1], a2 = ga[2], a3 = ga[3];
    uint4 b0 = gb[0], b1 = gb[1], b2 = gb[2], b3 = gb[3];
    __syncthreads();
    *(uint4*)&As[srow][skb +  0] = a0; *(uint4*)&As[srow][skb +  8] = a1;
    *(uint4*)&As[srow][skb + 16] = a2; *(uint4*)&As[srow][skb + 24] = a3;
    *(uint4*)&Bs[srow][skb +  0] = b0; *(uint4*)&Bs[srow][skb +  8] = b1;
    *(uint4*)&Bs[srow][skb + 16] = b2; *(uint4*)&Bs[srow][skb + 24] = b3;
    __syncthreads();
#pragma unroll
    for (int kk = 0; kk < 2; ++kk){
      const int kidx = kk * 32 + quad * 8;
      bf16x8 af[4], bfr[4];
      const int rA = wm * 64 + col, rB = wn * 64 + col;
#pragma unroll
      for (int mi = 0; mi < 4; ++mi) af[mi] = *(const bf16x8*)&As[rA + mi * 16][kidx];
#pragma unroll
      for (int ni = 0; ni < 4; ++ni) bfr[ni] = *(const bf16x8*)&Bs[rB + ni * 16][kidx];
#pragma unroll
      for (int mi = 0; mi < 4; ++mi)
#pragma unroll
        for (int ni = 0; ni < 4; ++ni)
          acc[mi][ni] = __builtin_amdgcn_mfma_f32_16x16x32_bf16(af[mi], bfr[ni], acc[mi][ni], 0, 0, 0);
    }
  }

  float part[4][4];
#pragma unroll
  for (int mi = 0; mi < 4; ++mi)
#pragma unroll
    for (int r = 0; r < 4; ++r) part[mi][r] = 0.f;
#pragma unroll
  for (int ni = 0; ni < 4; ++ni){
    int n = n0 + wn * 64 + ni * 16 + col;
    float b1v = ab1[n], w2v = aw2[n];
#pragma unroll
    for (int mi = 0; mi < 4; ++mi)
#pragma unroll
      for (int r = 0; r < 4; ++r)
        part[mi][r] += eluf(acc[mi][ni][r] + b1v) * w2v;
  }
#pragma unroll
  for (int msk = 1; msk <= 8; msk <<= 1)
#pragma unroll
    for (int mi = 0; mi < 4; ++mi)
#pragma unroll
      for (int r = 0; r < 4; ++r)
        part[mi][r] += __shfl_xor(part[mi][r], msk);
  if (col == 0){
#pragma unroll
    for (int mi = 0; mi < 4; ++mi)
#pragma unroll
      for (int r = 0; r < 4; ++r){
        int pi = m0 + wm * 64 + mi * 16 + quad * 4 + r;
        atomicAdd(&logits[pi * 4 + c], part[mi][r]);
      }
  }
}

// ------------- per-head D×D relation transforms: krel/vrel ----------------
__global__ __launch_bounds__(256) void rel_kernel(
    const float* __restrict__ Kt, const float* __restrict__ Vt,
    const float* __restrict__ arel, const float* __restrict__ mrel,
    float* __restrict__ krel, float* __restrict__ vrel)
{
  const int h = blockIdx.y, n0 = blockIdx.x * 32;
  __shared__ float Ams[32][33], Mms[32][33], Kr[32][33], Vr[32][33];
  const int tid = threadIdx.x;
  {
    int idx = tid * 4; int d = idx >> 5, e = idx & 31;
    float4 va = *(const float4*)(arel + h * 1024 + idx);
    float4 vm = *(const float4*)(mrel + h * 1024 + idx);
    Ams[d][e] = va.x; Ams[d][e+1] = va.y; Ams[d][e+2] = va.z; Ams[d][e+3] = va.w;
    Mms[d][e] = vm.x; Mms[d][e+1] = vm.y; Mms[d][e+2] = vm.z; Mms[d][e+3] = vm.w;
  }
  {
    int i = tid >> 3, d4 = (tid & 7) << 2;
    float4 vk = *(const float4*)(Kt + (size_t)(n0 + i) * 256 + h * 32 + d4);
    float4 vv = *(const float4*)(Vt + (size_t)(n0 + i) * 256 + h * 32 + d4);
    Kr[i][d4] = vk.x; Kr[i][d4+1] = vk.y; Kr[i][d4+2] = vk.z; Kr[i][d4+3] = vk.w;
    Vr[i][d4] = vv.x; Vr[i][d4+1] = vv.y; Vr[i][d4+2] = vv.z; Vr[i][d4+3] = vv.w;
  }
  __syncthreads();
  const int i = tid >> 3, e0 = (tid & 7) << 2;
  float aK[4] = {0,0,0,0}, aV[4] = {0,0,0,0};
#pragma unroll 8
  for (int d = 0; d < 32; ++d){
    float kv = Kr[i][d], vv = Vr[i][d];
#pragma unroll
    for (int e = 0; e < 4; ++e){
      aK[e] = fmaf(kv, Ams[d][e0 + e], aK[e]);
      aV[e] = fmaf(vv, Mms[d][e0 + e], aV[e]);
    }
  }
#pragma unroll
  for (int e = 0; e < 4; ++e){
    krel[(size_t)(n0 + i) * 256 + h * 32 + e0 + e] = aK[e];
    vrel[(size_t)(n0 + i) * 256 + h * 32 + e0 + e] = aV[e];
  }
}

// ----------------------------- CSR build ----------------------------------
__global__ void deg_kernel(const int* __restrict__ ei, int Er, int* __restrict__ deg){
  int e = blockIdx.x * 256 + threadIdx.x;
  if (e < Er) atomicAdd(&deg[ei[Er + e]], 1);
}

// one-block exclusive scan: ptr[0]=0, ptr[i+1]=sum deg[0..i]
__global__ void scan_kernel(const int* __restrict__ deg, int n, int* __restrict__ ptr){
  __shared__ int tmp[256];
  __shared__ int carry;
  int tid = threadIdx.x;
  if (tid == 0){ carry = 0; ptr[0] = 0; }
  __syncthreads();
  for (int base = 0; base < n; base += 256){
    int v = (base + tid < n) ? deg[base + tid] : 0;
    tmp[tid] = v; __syncthreads();
    for (int off = 1; off < 256; off <<= 1){
      int t = (tid >= off) ? tmp[tid - off] : 0;
      __syncthreads();
      tmp[tid] += t;
      __syncthreads();
    }
    if (base + tid < n) ptr[base + tid + 1] = carry + tmp[tid];
    __syncthreads();
    if (tid == 0) carry += tmp[255];
    __syncthreads();
  }
}

__global__ void icopy_kernel(const int* __restrict__ a, int* __restrict__ b, int n){
  int i = blockIdx.x * 256 + threadIdx.x;
  if (i < n) b[i] = a[i];
}

__global__ void csrfill_kernel(const int* __restrict__ ei, int Er,
                               int* __restrict__ cursor, int* __restrict__ csrc){
  int e = blockIdx.x * 256 + threadIdx.x;
  if (e >= Er) return;
  int pos = atomicAdd(&cursor[ei[Er + e]], 1);
  csrc[pos] = ei[e];
}

// --------- one wave per (dst,head): gather + online softmax + weighted sum
template<int ACCUM>
__global__ __launch_bounds__(256) void attn_csr(
    const int* __restrict__ ptr, const int* __restrict__ csrc, int Nd,
    const float* __restrict__ Q, const float* __restrict__ krel,
    const float* __restrict__ vrel, const float* __restrict__ prel,
    float* __restrict__ aggOut)
{
  int wid = (blockIdx.x * 256 + threadIdx.x) >> 6;
  if (wid >= Nd * 8) return;
  int lane = threadIdx.x & 63;
  int dst = wid >> 3, h = wid & 7;
  int f = lane & 31, eo = lane >> 5;
  float qv = Q[(size_t)dst * 256 + h * 32 + f];
  float sc = prel[h] * 0.17677669529663687f;   // 1/sqrt(32)
  int s0 = ptr[dst], s1 = ptr[dst + 1];
  float m = -INFINITY, d = 0.f, acc = 0.f;
  for (int e = s0 + eo; e < s1; e += 2){
    int src = csrc[e];
    float kv = krel[(size_t)src * 256 + h * 32 + f];
    float vv = vrel[(size_t)src * 256 + h * 32 + f];
    float p = qv * kv;
#pragma unroll
    for (int msk = 1; msk < 32; msk <<= 1) p += __shfl_xor(p, msk);
    float s = p * sc;
    float mn = fmaxf(m, s);
    float scale = expf(m - mn);      // first iter: exp(-inf)=0, d=acc=0 anyway
    float wgt = expf(s - mn);
    d = d * scale + wgt;
    acc = acc * scale + wgt * vv;
    m = mn;
  }
  // merge the two half-waves (lane ^ 32)
  float m2 = __shfl_xor(m, 32);
  float d2 = __shfl_xor(d, 32);
  float a2 = __shfl_xor(acc, 32);
  float mn = fmaxf(m, m2);
  float sc1 = (m  > -INFINITY) ? expf(m  - mn) : 0.f;
  float sc2 = (m2 > -INFINITY) ? expf(m2 - mn) : 0.f;
  d = d * sc1 + d2 * sc2;
  acc = acc * sc1 + a2 * sc2;
  if (eo == 0){
    float val = d > 0.f ? acc / d : 0.f;
    float* op = &aggOut[(size_t)dst * 256 + h * 32 + f];
    if (ACCUM) *op += val; else *op = val;
  }
}

// ------------------------------ pooling -----------------------------------
__global__ void pool_kernel(const float* __restrict__ xc, const float* __restrict__ xp,
                            float* __restrict__ hpool){
  int b = blockIdx.x, e = threadIdx.x;   // 256 threads
  float s = 0.f;
#pragma unroll
  for (int c = 0; c < 4; ++c) s += xc[(size_t)(b * 4 + c) * 256 + e];
  hpool[b * 512 + e] = s * 0.25f;
  float s2 = 0.f;
  for (int p = 0; p < 256; ++p) s2 += xp[(size_t)(b * 256 + p) * 256 + e];
  hpool[b * 512 + 256 + e] = s2 * (1.f / 256.f);
}

// ------------------------- outputs ---------------------------------------
__global__ void logsoftmax_out(const float* __restrict__ logits,
                               const int* __restrict__ action, float* __restrict__ out){
  int b = blockIdx.x, tid = threadIdx.x;
  const float* row = logits + b * 1024;
  __shared__ float red[256];
  float m = -INFINITY;
  for (int i = tid; i < 1024; i += 256) m = fmaxf(m, row[i]);
  red[tid] = m; __syncthreads();
  for (int s = 128; s > 0; s >>= 1){ if (tid < s) red[tid] = fmaxf(red[tid], red[tid + s]); __syncthreads(); }
  m = red[0]; __syncthreads();
  float s = 0.f;
  for (int i = tid; i < 1024; i += 256) s += expf(row[i] - m);
  red[tid] = s; __syncthreads();
  for (int st = 128; st > 0; st >>= 1){ if (tid < st) red[tid] += red[tid + st]; __syncthreads(); }
  if (tid == 0) out[b] = row[action[b]] - m - logf(red[0]);
}

__global__ void critic_out(const float* __restrict__ h2, const float* __restrict__ cw2,
                           const float* __restrict__ cb2, float* __restrict__ out){
  int b = blockIdx.x, tid = threadIdx.x;
  __shared__ float red[256];
  float s = 0.f;
  for (int i = tid; i < 512; i += 256) s += h2[b * 512 + i] * cw2[i];
  red[tid] = s; __syncthreads();
  for (int st = 128; st > 0; st >>= 1){ if (tid < st) red[tid] += red[tid + st]; __syncthreads(); }
  if (tid == 0) out[64 + b] = red[0] + cb2[0];
}

extern "C" void kernel_launch(void* const* d_in, const int* in_sizes, int n_in,
                              void* d_out, int out_size, void* d_ws, size_t ws_size,
                              hipStream_t stream)
{
  const float* x_crane = (const float*)d_in[0];
  const float* x_pile  = (const float*)d_in[1];
  const int* e_list[4] = {(const int*)d_in[2], (const int*)d_in[3],
                          (const int*)d_in[4], (const int*)d_in[5]};
  int E_cnt[4]; for (int r = 0; r < 4; ++r) E_cnt[r] = in_sizes[2 + r] / 2;
  const int*   batch_action = (const int*)d_in[6];
  const float* kqv_w[2] = {(const float*)d_in[8],  (const float*)d_in[10]};
  const float* kqv_b[2] = {(const float*)d_in[9],  (const float*)d_in[11]};
  const float* a_rel = (const float*)d_in[12];
  const float* m_rel = (const float*)d_in[13];
  const float* p_rel = (const float*)d_in[14];
  const float* out_w = (const float*)d_in[15];
  const float* out_b = (const float*)d_in[16];
  const float* skip  = (const float*)d_in[17];
  const float* aw0 = (const float*)d_in[18]; const float* ab0 = (const float*)d_in[19];
  const float* aw1 = (const float*)d_in[20]; const float* ab1 = (const float*)d_in[21];
  const float* aw2 = (const float*)d_in[22];
  const float* cw0 = (const float*)d_in[24]; const float* cb0 = (const float*)d_in[25];
  const float* cw1 = (const float*)d_in[26]; const float* cb1 = (const float*)d_in[27];
  const float* cw2 = (const float*)d_in[28]; const float* cb2 = (const float*)d_in[29];
  float* out = (float*)d_out;

  float* w = (float*)d_ws;
  size_t o = 0;
  auto A = [&](size_t n){ float* p = w + o; o += n; return p; };
  float* Kc = A(65536);     float* Qc = A(65536);     float* Vc = A(65536);
  float* Kp = A(4194304);   float* Qp = A(4194304);   float* Vp = A(4194304);
  float* krc = A(65536);    float* vrc = A(65536);
  float* krp = A(4194304);  float* vrp = A(4194304);
  float* aggc = A(65536);   float* aggp = A(4194304);
  float* xc0 = A(65536);    float* xc1 = A(65536);
  float* xp0 = A(4194304);  float* xp1 = A(4194304);
  float* alpha = A(2097152);
  float* segmax = A(131072); float* segsum = A(131072);
  float* hpool = A(32768);
  // ---- CSR layout inside alpha region (ints), live only during HGT ----
  int* ialpha = (int*)alpha;
  int* ptr_r[4]; int* cur_r[4]; int* src_r[4];
  ptr_r[0] = ialpha;            // 257   (cc)
  ptr_r[1] = ialpha + 512;      // 257   (pc)
  ptr_r[2] = ialpha + 1024;     // 16385 (cp)
  ptr_r[3] = ialpha + 17664;    // 16385 (pp)
  cur_r[0] = ialpha + 34304;    // 256
  cur_r[1] = ialpha + 34816;    // 256
  cur_r[2] = ialpha + 35328;    // 16384
  cur_r[3] = ialpha + 51712;    // 16384
  src_r[0] = ialpha + 68096;    // 1024
  src_r[1] = ialpha + 69120;    // 65536
  src_r[2] = ialpha + 134656;   // 65536
  src_r[3] = ialpha + 200192;   // 262144 (ends 462336 < 2,097,152)
  const int NdR[4] = {NCR, NCR, NPI, NPI};
  // ---- post-HGT overlays (all verified disjoint from live xc1/xp1/hpool) ----
  float*          P0p  = w;                        // [0, 16,777,216) f32 — dead
  unsigned short* h0c  = (unsigned short*)(w + 16777216); // [16.77M, 25.17M) f32-equiv
  unsigned short* aw1T = (unsigned short*)xp0;     // in dead xp0
  float*          P0cp = alpha;                    // 262,144
  float*          P0c  = alpha + 262144;           // 262,144
  float*          logits = segmax;                 // 65,536
  float*          ch1 = segsum;                    // 32,768
  float*          ch2 = segsum + 65536;            // 32,768

  // ---- build CSR once (edges shared by both layers) ----
  fill_kernel<<<132, 256, 0, stream>>>((float*)cur_r[0], 0.f, 33792);  // zero all deg arrays
  for (int r = 0; r < 4; ++r)
    deg_kernel<<<(E_cnt[r] + 255) / 256, 256, 0, stream>>>(e_list[r], E_cnt[r], cur_r[r]);
  for (int r = 0; r < 4; ++r)
    scan_kernel<<<1, 256, 0, stream>>>(cur_r[r], NdR[r], ptr_r[r]);
  for (int r = 0; r < 4; ++r)
    icopy_kernel<<<(NdR[r] + 255) / 256, 256, 0, stream>>>(ptr_r[r], cur_r[r], NdR[r]);
  for (int r = 0; r < 4; ++r)
    csrfill_kernel<<<(E_cnt[r] + 255) / 256, 256, 0, stream>>>(e_list[r], E_cnt[r], cur_r[r], src_r[r]);

  for (int l = 0; l < 2; ++l){
    const float* xc_in = l ? xc0 : x_crane;
    const float* xp_in = l ? xp0 : x_pile;
    const int Kd = l ? 256 : 64;
    for (int j = 0; j < 3; ++j){
      float* Cc = (j == 0) ? Kc : (j == 1) ? Qc : Vc;
      float* Cp = (j == 0) ? Kp : (j == 1) ? Qp : Vp;
      gemm128<0><<<dim3(2, 2),   256, 0, stream>>>(xc_in, Kd, kqv_w[l] + (size_t)j * Kd * 256,       256, kqv_b[l] + j * 256,       Cc, 256, NCR, 256, Kd);
      gemm128<0><<<dim3(2, 128), 256, 0, stream>>>(xp_in, Kd, kqv_w[l] + (size_t)(3 + j) * Kd * 256, 256, kqv_b[l] + (3 + j) * 256, Cp, 256, NPI, 256, Kd);
    }
    // r0: cc (src crane, dst crane) — covers all cranes, ACCUM=0
    rel_kernel<<<dim3(NCR / 32, 8), 256, 0, stream>>>(Kc, Vc,
        a_rel + (size_t)(l * 4 + 0) * 8192, m_rel + (size_t)(l * 4 + 0) * 8192, krc, vrc);
    attn_csr<0><<<NCR * 2, 256, 0, stream>>>(ptr_r[0], src_r[0], NCR, Qc, krc, vrc,
        p_rel + (l * 4 + 0) * 8, aggc);
    // r1: pc (src pile, dst crane) — ACCUM=1
    rel_kernel<<<dim3(NPI / 32, 8), 256, 0, stream>>>(Kp, Vp,
        a_rel + (size_t)(l * 4 + 1) * 8192, m_rel + (size_t)(l * 4 + 1) * 8192, krp, vrp);
    attn_csr<1><<<NCR * 2, 256, 0, stream>>>(ptr_r[1], src_r[1], NCR, Qc, krp, vrp,
        p_rel + (l * 4 + 1) * 8, aggc);
    // r2: cp (src crane, dst pile) — covers all piles, ACCUM=0
    rel_kernel<<<dim3(NCR / 32, 8), 256, 0, stream>>>(Kc, Vc,
        a_rel + (size_t)(l * 4 + 2) * 8192, m_rel + (size_t)(l * 4 + 2) * 8192, krc, vrc);
    attn_csr<0><<<NPI * 2, 256, 0, stream>>>(ptr_r[2], src_r[2], NPI, Qp, krc, vrc,
        p_rel + (l * 4 + 2) * 8, aggp);
    // r3: pp (src pile, dst pile) — ACCUM=1
    rel_kernel<<<dim3(NPI / 32, 8), 256, 0, stream>>>(Kp, Vp,
        a_rel + (size_t)(l * 4 + 3) * 8192, m_rel + (size_t)(l * 4 + 3) * 8192, krp, vrp);
    attn_csr<1><<<NPI * 2, 256, 0, stream>>>(ptr_r[3], src_r[3], NPI, Qp, krp, vrp,
        p_rel + (l * 4 + 3) * 8, aggp);

    gelu_kernel<<<256,   256, 0, stream>>>(aggc, 65536);
    gelu_kernel<<<16384, 256, 0, stream>>>(aggp, 4194304);
    gemm128<0><<<dim3(2, 2),   256, 0, stream>>>(aggc, 256, out_w + (size_t)(l * 2 + 0) * 65536, 256, out_b + (l * 2 + 0) * 256, Kc, 256, NCR, 256, 256);
    gemm128<0><<<dim3(2, 128), 256, 0, stream>>>(aggp, 256, out_w + (size_t)(l * 2 + 1) * 65536, 256, out_b + (l * 2 + 1) * 256, Kp, 256, NPI, 256, 256);
    skip_elu_kernel<<<256,   256, 0, stream>>>(Kc, xc_in, skip + l * 2 + 0, l, l ? xc1 : xc0, 65536);
    skip_elu_kernel<<<16384, 256, 0, stream>>>(Kp, xp_in, skip + l * 2 + 1, l, l ? xp1 : xp0, 4194304);
  }

  // ---- pooling + actor layer0 decomposition ----
  pool_kernel<<<64, 256, 0, stream>>>(xc1, xp1, hpool);
  gemm128<0><<<dim3(8, 2), 256, 0, stream>>>(xc1, 256, aw0, 1024, nullptr, P0c, 1024, NCR, 1024, 256);
  p0cp_kernel<<<256, 256, 0, stream>>>(hpool, aw0, ab0, P0c, P0cp);
  aw1t_kernel<<<dim3(32, 32), 256, 0, stream>>>(aw1, aw1T);
  gemm128<0><<<dim3(8, 128), 256, 0, stream>>>(xp1, 256, aw0 + (size_t)256 * 1024, 1024, nullptr, P0p, 1024, NPI, 1024, 256);
  fill_kernel<<<256, 256, 0, stream>>>(logits, 0.f, 65536);
  for (int c = 0; c < 4; ++c){
    h0_build<<<8192, 256, 0, stream>>>(P0p, P0cp, c, h0c);
    actor_mfma<<<dim3(8, 128), 256, 0, stream>>>(h0c, aw1T, ab1, aw2, c, logits);
  }
  logsoftmax_out<<<64, 256, 0, stream>>>(logits, batch_action, out);

  // critic
  gemm128<1><<<dim3(4, 1), 256, 0, stream>>>(hpool, 512, cw0, 512, cb0, ch1, 512, 64, 512, 512);
  gemm128<1><<<dim3(4, 1), 256, 0, stream>>>(ch1,   512, cw1, 512, cb1, ch2, 512, 64, 512, 512);
  critic_out<<<64, 256, 0, stream>>>(ch2, cw2, cb2, out);
}